// Round 1
// baseline (29.882 us; speedup 1.0000x reference)
//
#include <hip/hip_runtime.h>
#include <math.h>

#define E_ALL 4100
#define NENT_C 4096
#define DIM 128

// Kernel 1: u[j] = e_all[j]·w1, v[j] = e_all[j]·w2 for j in [0, 4100)
// One wave (64 lanes) per row; each lane handles 2 consecutive floats (float2).
__global__ void k_uv(const float* __restrict__ e_table,
                     const float* __restrict__ anon,
                     const float* __restrict__ fc_w,
                     float* __restrict__ u, float* __restrict__ v)
{
    const int lane = threadIdx.x & 63;
    const int wave = threadIdx.x >> 6;
    const float w1a = fc_w[2 * lane];
    const float w1b = fc_w[2 * lane + 1];
    const float w2a = fc_w[DIM + 2 * lane];
    const float w2b = fc_w[DIM + 2 * lane + 1];
    const int jbase = blockIdx.x * 32 + wave * 8;
    for (int r = 0; r < 8; ++r) {
        const int j = jbase + r;
        if (j >= E_ALL) return;  // uniform across the wave (j independent of lane)
        const float* row = (j < NENT_C) ? (e_table + (size_t)j * DIM)
                                        : (anon + (size_t)(j - NENT_C) * DIM);
        const float2 e = *reinterpret_cast<const float2*>(row + 2 * lane);
        float pu = e.x * w1a + e.y * w1b;
        float pv = e.x * w2a + e.y * w2b;
#pragma unroll
        for (int o = 32; o; o >>= 1) {
            pu += __shfl_xor(pu, o);
            pv += __shfl_xor(pv, o);
        }
        if (lane == 0) { u[j] = pu; v[j] = pv; }
    }
}

// Kernel 2: single block, 512 threads (8 waves).
//   result[b] = max_j sigmoid(u[j] + s_r[b] + b0 + Vmax) * sigmoid(v[j] + s_c[b] + b0)
//   loss = mean_b -log(1 - result[b] + 1e-10)
__global__ void k_final(const float* __restrict__ u, const float* __restrict__ v,
                        const int* __restrict__ x,
                        const float* __restrict__ c_table,
                        const float* __restrict__ r_table,
                        const float* __restrict__ fc_w,
                        const float* __restrict__ fc_b,
                        float* __restrict__ out)
{
    __shared__ float s_sr[8], s_sc[8], s_vw[8], s_vmax;
    __shared__ float s_wm[64];
    __shared__ float s_m[8];
    const int tid = threadIdx.x;
    const int lane = tid & 63;
    const int wave = tid >> 6;
    const float b0 = fc_b[0];

    // s_r[b] = r_table[x[b,0]]·w1,  s_c[b] = c_table[x[b,1]]·w1 ; wave w handles b=w
    {
        const int b = wave;
        const int ri = x[2 * b];
        const int ci = x[2 * b + 1];
        const float w1a = fc_w[2 * lane];
        const float w1b = fc_w[2 * lane + 1];
        const float2 rr = *reinterpret_cast<const float2*>(r_table + (size_t)ri * DIM + 2 * lane);
        const float2 cc = *reinterpret_cast<const float2*>(c_table + (size_t)ci * DIM + 2 * lane);
        float pr = rr.x * w1a + rr.y * w1b;
        float pc = cc.x * w1a + cc.y * w1b;
#pragma unroll
        for (int o = 32; o; o >>= 1) {
            pr += __shfl_xor(pr, o);
            pc += __shfl_xor(pc, o);
        }
        if (lane == 0) { s_sr[b] = pr; s_sc[b] = pc; }
    }

    // Vmax = max_j v[j]
    float vm = -INFINITY;
    for (int j = tid; j < E_ALL; j += 512) vm = fmaxf(vm, v[j]);
#pragma unroll
    for (int o = 32; o; o >>= 1) vm = fmaxf(vm, __shfl_xor(vm, o));
    if (lane == 0) s_vw[wave] = vm;
    __syncthreads();
    if (tid == 0) {
        float mm = -INFINITY;
        for (int w = 0; w < 8; ++w) mm = fmaxf(mm, s_vw[w]);
        s_vmax = mm;
    }
    __syncthreads();

    const float vmax = s_vmax;
    float sr[8], sc[8];
#pragma unroll
    for (int b = 0; b < 8; ++b) {
        sr[b] = s_sr[b] + b0 + vmax;   // argument offset for the aj-side sigmoid
        sc[b] = s_sc[b] + b0;          // argument offset for the c_fs-side sigmoid
    }

    float m[8];
#pragma unroll
    for (int b = 0; b < 8; ++b) m[b] = -INFINITY;

    for (int j = tid; j < E_ALL; j += 512) {
        const float uj = u[j];
        const float vj = v[j];
#pragma unroll
        for (int b = 0; b < 8; ++b) {
            const float t1 = 1.0f / (1.0f + expf(-(uj + sr[b])));
            const float t2 = 1.0f / (1.0f + expf(-(vj + sc[b])));
            m[b] = fmaxf(m[b], t1 * t2);
        }
    }

    // wave-level max reduce for each b, then cross-wave
#pragma unroll
    for (int b = 0; b < 8; ++b) {
        float t = m[b];
#pragma unroll
        for (int o = 32; o; o >>= 1) t = fmaxf(t, __shfl_xor(t, o));
        if (lane == 0) s_wm[b * 8 + wave] = t;
    }
    __syncthreads();
    if (tid < 64) {
        const int b = tid >> 3;
        float t = s_wm[tid];  // s_wm[b*8 + w] with w = tid&7
#pragma unroll
        for (int o = 1; o < 8; o <<= 1) t = fmaxf(t, __shfl_xor(t, o));
        if ((tid & 7) == 0) s_m[b] = t;
    }
    __syncthreads();
    if (tid == 0) {
        float acc = 0.0f;
        for (int b = 0; b < 8; ++b) acc += -logf(1.0f - s_m[b] + 1e-10f);
        out[0] = acc * (1.0f / 8.0f);
    }
}

extern "C" void kernel_launch(void* const* d_in, const int* in_sizes, int n_in,
                              void* d_out, int out_size, void* d_ws, size_t ws_size,
                              hipStream_t stream) {
    const int*   x        = (const int*)d_in[0];
    const float* anon     = (const float*)d_in[1];
    const float* c_table  = (const float*)d_in[2];
    const float* r_table  = (const float*)d_in[3];
    const float* e_table  = (const float*)d_in[4];
    const float* fc_w     = (const float*)d_in[5];
    const float* fc_b     = (const float*)d_in[6];
    float* out = (float*)d_out;

    float* u = (float*)d_ws;          // 4100 floats
    float* v = u + E_ALL;             // 4100 floats

    const int blocks = (E_ALL + 31) / 32;  // 129
    k_uv<<<blocks, 256, 0, stream>>>(e_table, anon, fc_w, u, v);
    k_final<<<1, 512, 0, stream>>>(u, v, x, c_table, r_table, fc_w, fc_b, out);
}